// Round 1
// baseline (612.764 us; speedup 1.0000x reference)
//
#include <hip/hip_runtime.h>
#include <cstdint>
#include <cstddef>

// HetroGNN fused kernel: h = tanh(W_w @ concat(rel,ent) + b_w); s = u.h + b_u;
// att = softmax_n(mask ? -inf : s); out = tanh(sum_n att * ent).
// Strategy: bf16 MFMA with hi/lo split precision (3 passes -> ~fp32 accuracy),
// W held as persistent per-wave VGPR fragments, A staged per-batch in LDS.

#define WAVES 4
#define BLOCK 256
#define NPAD 32
#define LDS_STRIDE 264  // 256 + 8 ushort pad: breaks LDS bank conflicts, keeps 16B align

typedef __attribute__((ext_vector_type(8))) short short8;
typedef __attribute__((ext_vector_type(4))) float f32x4;

__device__ __forceinline__ float fast_tanh(float x) {
  // tanh(x) = 1 - 2/(e^{2x}+1); exact saturation at +/-inf
  float e = __expf(2.0f * x);
  return 1.0f - 2.0f / (e + 1.0f);
}

__device__ __forceinline__ void cvt_hilo(float f, unsigned short& h, unsigned short& l) {
  unsigned int bits = __float_as_uint(f);
  h = (unsigned short)(bits >> 16);  // truncated bf16 hi
  float r = f - __uint_as_float(bits & 0xFFFF0000u);
  l = (unsigned short)(__float_as_uint(r) >> 16);  // bf16 of residual
}

__global__ __launch_bounds__(BLOCK, 2) void hetrognn_kernel(
    const float* __restrict__ rel, const float* __restrict__ ent,
    const int* __restrict__ mask, const float* __restrict__ Ww,
    const float* __restrict__ bw, const float* __restrict__ Wu,
    const float* __restrict__ bu, float* __restrict__ out, int Btot) {
  __shared__ unsigned short Ahi[NPAD * LDS_STRIDE];
  __shared__ unsigned short Alo[NPAD * LDS_STRIDE];
  __shared__ float pscore[WAVES][NPAD];
  __shared__ float att[NPAD];

  const int tid = threadIdx.x;
  const int wave = tid >> 6;
  const int lane = tid & 63;
  const int l15 = lane & 15;
  const int quad = lane >> 4;

  // ---- one-time: persistent W fragments (B-operand layout: n=lane&15, k=quad*8+j)
  short8 whi[2][8], wlo[2][8];
  float bwv[2], uv[2];
#pragma unroll
  for (int c = 0; c < 2; ++c) {
    const int d = wave * 32 + c * 16 + l15;
    bwv[c] = bw[d];
    uv[c] = Wu[d];
#pragma unroll
    for (int ks = 0; ks < 8; ++ks) {
      const float* wp = Ww + d * 256 + ks * 32 + quad * 8;
#pragma unroll
      for (int j = 0; j < 8; ++j) {
        unsigned short h, l;
        cvt_hilo(wp[j], h, l);
        whi[c][ks][j] = (short)h;
        wlo[c][ks][j] = (short)l;
      }
    }
  }
  const float buv = bu[0];

  for (int b = blockIdx.x; b < Btot; b += gridDim.x) {
    const float* rel_b = rel + (size_t)b * 3840;
    const float* ent_b = ent + (size_t)b * 3840;

    // ---- stage concat rows (32 x 256, rows 30/31 zero-pad) as bf16 hi/lo ----
#pragma unroll
    for (int it = 0; it < 8; ++it) {
      const int i4 = tid + it * 256;   // float4 index 0..2047
      const int row = i4 >> 6;         // 64 float4 per 256-wide row
      const int k4 = (i4 & 63) << 2;   // feature offset, multiple of 4
      float4 v = make_float4(0.f, 0.f, 0.f, 0.f);
      if (row < 30) {
        const float* src = (k4 < 128) ? (rel_b + row * 128 + k4)
                                      : (ent_b + row * 128 + (k4 - 128));
        v = *(const float4*)src;
      }
      unsigned short h0, h1, h2, h3, l0, l1, l2, l3;
      cvt_hilo(v.x, h0, l0);
      cvt_hilo(v.y, h1, l1);
      cvt_hilo(v.z, h2, l2);
      cvt_hilo(v.w, h3, l3);
      uint2 hh, ll;
      hh.x = (unsigned int)h0 | ((unsigned int)h1 << 16);
      hh.y = (unsigned int)h2 | ((unsigned int)h3 << 16);
      ll.x = (unsigned int)l0 | ((unsigned int)l1 << 16);
      ll.y = (unsigned int)l2 | ((unsigned int)l3 << 16);
      *(uint2*)&Ahi[row * LDS_STRIDE + k4] = hh;
      *(uint2*)&Alo[row * LDS_STRIDE + k4] = ll;
    }
    __syncthreads();

    // ---- MFMA: each wave computes 32 rows x its 32-col d-slice ----
#pragma unroll
    for (int mt = 0; mt < 2; ++mt) {
      f32x4 acc0 = {0.f, 0.f, 0.f, 0.f};
      f32x4 acc1 = {0.f, 0.f, 0.f, 0.f};
      const int arow = mt * 16 + l15;
      const unsigned short* abase = &Ahi[arow * LDS_STRIDE + quad * 8];
      const unsigned short* lbase = &Alo[arow * LDS_STRIDE + quad * 8];
#pragma unroll
      for (int ks = 0; ks < 8; ++ks) {
        short8 ah = *(const short8*)(abase + ks * 32);
        short8 al = *(const short8*)(lbase + ks * 32);
        acc0 = __builtin_amdgcn_mfma_f32_16x16x32_bf16(ah, whi[0][ks], acc0, 0, 0, 0);
        acc1 = __builtin_amdgcn_mfma_f32_16x16x32_bf16(ah, whi[1][ks], acc1, 0, 0, 0);
        acc0 = __builtin_amdgcn_mfma_f32_16x16x32_bf16(al, whi[0][ks], acc0, 0, 0, 0);
        acc1 = __builtin_amdgcn_mfma_f32_16x16x32_bf16(al, whi[1][ks], acc1, 0, 0, 0);
        acc0 = __builtin_amdgcn_mfma_f32_16x16x32_bf16(ah, wlo[0][ks], acc0, 0, 0, 0);
        acc1 = __builtin_amdgcn_mfma_f32_16x16x32_bf16(ah, wlo[1][ks], acc1, 0, 0, 0);
      }
      // epilogue: h = tanh(hpre + bw); partial score = sum_d u[d]*h over this wave's 32 d
      float part[4];
#pragma unroll
      for (int reg = 0; reg < 4; ++reg) {
        float h0 = fast_tanh(acc0[reg] + bwv[0]);
        float h1 = fast_tanh(acc1[reg] + bwv[1]);
        part[reg] = uv[0] * h0 + uv[1] * h1;
      }
      // butterfly-reduce across the 16 lanes of each quad (d dimension)
#pragma unroll
      for (int m = 1; m < 16; m <<= 1) {
#pragma unroll
        for (int reg = 0; reg < 4; ++reg) part[reg] += __shfl_xor(part[reg], m, 64);
      }
      float v = (l15 == 0) ? part[0] : (l15 == 1) ? part[1] : (l15 == 2) ? part[2] : part[3];
      if (l15 < 4) pscore[wave][mt * 16 + quad * 4 + l15] = v;
    }
    __syncthreads();

    // ---- softmax over n (one wave's first 32 lanes) ----
    if (tid < 32) {
      const int n = tid;
      float raw = pscore[0][n] + pscore[1][n] + pscore[2][n] + pscore[3][n] + buv;
      const bool valid = (n < 30) && (mask[(size_t)b * 30 + n] == 0);
      float sc = valid ? raw : -INFINITY;
      float mx = sc;
#pragma unroll
      for (int m = 1; m < 32; m <<= 1) mx = fmaxf(mx, __shfl_xor(mx, m, 64));
      float e = valid ? __expf(sc - mx) : 0.f;
      float sm = e;
#pragma unroll
      for (int m = 1; m < 32; m <<= 1) sm += __shfl_xor(sm, m, 64);
      att[n] = e / sm;
    }
    __syncthreads();

    // ---- output: out[b,d] = tanh(sum_n att[n] * ent[b,n,d]) ----
    if (tid < 128) {
      const int d = tid;
      const float* ep = ent_b + d;
      float acc = 0.f;
#pragma unroll
      for (int n = 0; n < 30; ++n) acc += att[n] * ep[n * 128];
      out[(size_t)b * 128 + d] = fast_tanh(acc);
    }
    __syncthreads();  // protect LDS before next batch's staging
  }
}

extern "C" void kernel_launch(void* const* d_in, const int* in_sizes, int n_in,
                              void* d_out, int out_size, void* d_ws, size_t ws_size,
                              hipStream_t stream) {
  const float* rel = (const float*)d_in[0];
  const float* ent = (const float*)d_in[1];
  const int* mask = (const int*)d_in[2];
  const float* Ww = (const float*)d_in[3];
  const float* bw = (const float*)d_in[4];
  const float* Wu = (const float*)d_in[5];
  const float* bu = (const float*)d_in[6];
  float* out = (float*)d_out;
  const int Btot = in_sizes[0] / 3840;  // B*N*D / (30*128)
  const int grid = 2048;
  hipLaunchKernelGGL(hetrognn_kernel, dim3(grid), dim3(BLOCK), 0, stream,
                     rel, ent, mask, Ww, bw, Wu, bu, out, Btot);
}